// Round 1
// baseline (13836.263 us; speedup 1.0000x reference)
//
#include <hip/hip_runtime.h>

#define NN 256
#define INFV 1e30f

// ---- mask format handling (bool may arrive as bytes, int32, or float32) ----
__device__ __forceinline__ int mask_fmt(const void* m) {
    int w0 = ((const int*)m)[0];          // mask[0][0] is always true (lengths >= N/2)
    if (w0 == 1) return 0;                // int32 0/1
    if (w0 == 0x3F800000) return 1;       // float32 1.0f
    return 2;                             // 1-byte bool
}
__device__ __forceinline__ bool mask_at(const void* m, int fmt, int idx) {
    if (fmt == 0) return ((const int*)m)[idx] != 0;
    if (fmt == 1) return ((const float*)m)[idx] != 0.0f;
    return ((const unsigned char*)m)[idx] != 0;
}

// ---- tiled transpose + mask: ws[b][i][j] = mask[b][i] ? costs[b][j][i] : 0 ----
__global__ void transpose_mask_kernel(const float* __restrict__ costs,
                                      const void* __restrict__ mask,
                                      float* __restrict__ ws) {
    __shared__ float tile[32][33];
    const int b  = blockIdx.z;
    const int i0 = blockIdx.x * 32;
    const int j0 = blockIdx.y * 32;
    const int tx = threadIdx.x;   // 0..31
    const int ty = threadIdx.y;   // 0..7
    const int fmt = mask_fmt(mask);
    const float* Cb = costs + (size_t)b * NN * NN;
    float* Wb = ws + (size_t)b * NN * NN;

    #pragma unroll
    for (int k = 0; k < 32; k += 8) {
        // read costs[b][j][i], coalesced in i(=tx)
        tile[ty + k][tx] = Cb[(size_t)(j0 + ty + k) * NN + (i0 + tx)];
    }
    __syncthreads();
    #pragma unroll
    for (int k = 0; k < 32; k += 8) {
        const int i = i0 + ty + k;
        const int j = j0 + tx;
        const bool mv = mask_at(mask, fmt, b * NN + i);
        // write ws[b][i][j], coalesced in j(=tx); value = costs[b][j][i]
        Wb[(size_t)i * NN + j] = mv ? tile[tx][ty + k] : 0.0f;
    }
}

// ---- exact JV LAP, one block (1 wave, 64 lanes) per batch, 4 cols/lane ----
template <bool USE_WS>
__global__ __launch_bounds__(64)
void lap_kernel(const float* __restrict__ costs,
                const void* __restrict__ mask,
                const float* __restrict__ cmat,
                int* __restrict__ out) {
    const int b    = blockIdx.x;
    const int lane = threadIdx.x;   // 0..63; lane owns columns/rows lane*4 .. lane*4+3

    __shared__ float u_s[NN];
    __shared__ float sp_s[NN];
    __shared__ int   path_s[NN];
    __shared__ int   c4r_s[NN];   // col4row
    __shared__ int   r4c_s[NN];   // row4col

    const int fmt = mask_fmt(mask);

    // n = count of valid objects (mask is prefix-true)
    int nloc = 0;
    #pragma unroll
    for (int r = 0; r < 4; ++r)
        nloc += mask_at(mask, fmt, b * NN + lane * 4 + r) ? 1 : 0;
    #pragma unroll
    for (int off = 32; off; off >>= 1) nloc += __shfl_xor(nloc, off);
    const int n = nloc;

    #pragma unroll
    for (int r = 0; r < 4; ++r) {
        const int c = lane * 4 + r;
        u_s[c] = 0.0f;
        c4r_s[c] = -1;
        r4c_s[c] = -1;
    }
    float v[4] = {0.0f, 0.0f, 0.0f, 0.0f};
    __syncthreads();

    const float* CM = cmat + (size_t)b * NN * NN;   // transposed+masked (ws path)
    const float* CB = costs + (size_t)b * NN * NN;  // raw (fallback path)

    for (int cur = 0; cur < NN; ++cur) {
        // ---- Dijkstra (shortest augmenting path), bit-exact vs reference ----
        float sp[4]  = {INFV, INFV, INFV, INFV};
        int  path[4] = {-1, -1, -1, -1};
        bool SC[4]   = {false, false, false, false};
        bool SR[4]   = {false, false, false, false};
        int   i      = cur;
        float minVal = 0.0f;
        int   sink   = -1;

        while (sink < 0) {
            if ((i >> 2) == lane) SR[i & 3] = true;
            const float u_i = u_s[i];

            float cc[4];
            if (USE_WS) {
                const float4 c4 = *reinterpret_cast<const float4*>(CM + (size_t)i * NN + lane * 4);
                cc[0] = c4.x; cc[1] = c4.y; cc[2] = c4.z; cc[3] = c4.w;
            } else {
                if (i < n) {
                    #pragma unroll
                    for (int r = 0; r < 4; ++r)
                        cc[r] = CB[(size_t)(lane * 4 + r) * NN + i];
                } else {
                    #pragma unroll
                    for (int r = 0; r < 4; ++r) cc[r] = 0.0f;
                }
            }

            float bestv = INFV;
            int   bestc = NN;
            #pragma unroll
            for (int r = 0; r < 4; ++r) {
                // exact op order of reference: ((minVal + c) - u_i) - v_j
                const float rr = minVal + cc[r] - u_i - v[r];
                if (!SC[r] && rr < sp[r]) { sp[r] = rr; path[r] = i; }
                const float m = SC[r] ? INFV : sp[r];
                if (m < bestv) { bestv = m; bestc = lane * 4 + r; }  // strict < keeps lowest r
            }
            // wave argmin, first-index tie-break (matches jnp.argmin)
            #pragma unroll
            for (int off = 32; off; off >>= 1) {
                const float ov = __shfl_xor(bestv, off);
                const int   oc = __shfl_xor(bestc, off);
                if (ov < bestv || (ov == bestv && oc < bestc)) { bestv = ov; bestc = oc; }
            }
            minVal = bestv;
            const int j = bestc;
            if ((j >> 2) == lane) SC[j & 3] = true;
            const int nxt = r4c_s[j];
            if (nxt < 0) sink = j;
            else         i = nxt;
        }

        // dump per-lane sp/path for cross-lane gathers
        #pragma unroll
        for (int r = 0; r < 4; ++r) {
            sp_s[lane * 4 + r]   = sp[r];
            path_s[lane * 4 + r] = path[r];
        }
        __syncthreads();

        // ---- dual updates (same elementwise float ops as reference) ----
        #pragma unroll
        for (int r = 0; r < 4; ++r) {
            const int row = lane * 4 + r;
            if (SR[r]) {
                float du;
                if (row == cur) {
                    du = minVal;
                } else {
                    int c4 = c4r_s[row];
                    c4 = c4 < 0 ? 0 : c4;           // clip like reference
                    du = minVal - sp_s[c4];
                }
                u_s[row] = u_s[row] + du;
            }
            if (SC[r]) v[r] = v[r] - (minVal - sp[r]);
        }
        __syncthreads();

        // ---- augment along alternating path (serial walk, lane 0) ----
        if (lane == 0) {
            int j = sink;
            while (true) {
                const int ii = path_s[j];
                r4c_s[j] = ii;
                const int jn = c4r_s[ii];
                c4r_s[ii] = j;
                if (ii == cur) break;
                j = jn;
            }
        }
        __syncthreads();
    }

    // ---- emit output: valid rows -> col4row; invalid rows -> unused cols ascending ----
    int* ob = out + b * NN;
    #pragma unroll
    for (int r = 0; r < 4; ++r) {
        const int row = lane * 4 + r;
        if (row < n) ob[row] = c4r_s[row];
    }
    if (lane == 0) {
        int cnt = 0;
        for (int c = 0; c < NN; ++c) {
            if (r4c_s[c] >= n) {    // column assigned to an invalid row => unused
                ob[n + cnt] = c;
                ++cnt;
            }
        }
    }
}

extern "C" void kernel_launch(void* const* d_in, const int* in_sizes, int n_in,
                              void* d_out, int out_size, void* d_ws, size_t ws_size,
                              hipStream_t stream) {
    const float* costs = (const float*)d_in[0];
    const void*  mask  = d_in[1];
    int*         out   = (int*)d_out;

    const int B = in_sizes[1] / NN;   // in_sizes[1] = B*N
    const size_t need = (size_t)B * NN * NN * sizeof(float);

    if (ws_size >= need && d_ws != nullptr) {
        float* ws = (float*)d_ws;
        transpose_mask_kernel<<<dim3(NN / 32, NN / 32, B), dim3(32, 8), 0, stream>>>(costs, mask, ws);
        lap_kernel<true><<<dim3(B), dim3(64), 0, stream>>>(costs, mask, ws, out);
    } else {
        lap_kernel<false><<<dim3(B), dim3(64), 0, stream>>>(costs, mask, nullptr, out);
    }
}

// Round 3
// 5930.822 us; speedup vs baseline: 2.3329x; 2.3329x over previous
//
#include <hip/hip_runtime.h>

#define NN 256
#define INFV 1e30f

// ---- mask format handling (bool may arrive as bytes, int32, or float32) ----
__device__ __forceinline__ int mask_fmt(const void* m) {
    int w0 = ((const int*)m)[0];          // mask[0][0] is always true (lengths >= N/2)
    if (w0 == 1) return 0;                // int32 0/1
    if (w0 == 0x3F800000) return 1;       // float32 1.0f
    return 2;                             // 1-byte bool
}
__device__ __forceinline__ bool mask_at(const void* m, int fmt, int idx) {
    if (fmt == 0) return ((const int*)m)[idx] != 0;
    if (fmt == 1) return ((const float*)m)[idx] != 0.0f;
    return ((const unsigned char*)m)[idx] != 0;
}

// ---- tiled transpose + mask: ws[b][i][j] = mask[b][i] ? costs[b][j][i] : 0 ----
__global__ void transpose_mask_kernel(const float* __restrict__ costs,
                                      const void* __restrict__ mask,
                                      float* __restrict__ ws) {
    __shared__ float tile[32][33];
    const int b  = blockIdx.z;
    const int i0 = blockIdx.x * 32;
    const int j0 = blockIdx.y * 32;
    const int tx = threadIdx.x;   // 0..31
    const int ty = threadIdx.y;   // 0..7
    const int fmt = mask_fmt(mask);
    const float* Cb = costs + (size_t)b * NN * NN;
    float* Wb = ws + (size_t)b * NN * NN;

    #pragma unroll
    for (int k = 0; k < 32; k += 8) {
        tile[ty + k][tx] = Cb[(size_t)(j0 + ty + k) * NN + (i0 + tx)];
    }
    __syncthreads();
    #pragma unroll
    for (int k = 0; k < 32; k += 8) {
        const int i = i0 + ty + k;
        const int j = j0 + tx;
        const bool mv = mask_at(mask, fmt, b * NN + i);
        Wb[(size_t)i * NN + j] = mv ? tile[tx][ty + k] : 0.0f;
    }
}

// ---------- cross-lane helpers ----------
__device__ __forceinline__ int rl(int v, int lane) {
    return __builtin_amdgcn_readlane(v, lane);
}
__device__ __forceinline__ float rlf(float v, int lane) {
    return __int_as_float(__builtin_amdgcn_readlane(__float_as_int(v), lane));
}
// read element idx (uniform, 0..255) from a distributed array: lane k holds elems 4k..4k+3
__device__ __forceinline__ int read4i(const int a[4], int idx) {
    const int lane = idx >> 2;
    const int v0 = rl(a[0], lane), v1 = rl(a[1], lane);
    const int v2 = rl(a[2], lane), v3 = rl(a[3], lane);
    const int lo = (idx & 1) ? v1 : v0;
    const int hi = (idx & 1) ? v3 : v2;
    return (idx & 2) ? hi : lo;
}
__device__ __forceinline__ float read4f(const float a[4], int idx) {
    const int lane = idx >> 2;
    const int v0 = rl(__float_as_int(a[0]), lane), v1 = rl(__float_as_int(a[1]), lane);
    const int v2 = rl(__float_as_int(a[2]), lane), v3 = rl(__float_as_int(a[3]), lane);
    const int lo = (idx & 1) ? v1 : v0;
    const int hi = (idx & 1) ? v3 : v2;
    return __int_as_float((idx & 2) ? hi : lo);
}
// write val to distributed array element idx (idx uniform)
__device__ __forceinline__ void write4i(int (&a)[4], int idx, int val, int lane) {
    if (lane == (idx >> 2)) {
        switch (idx & 3) {
            case 0: a[0] = val; break;
            case 1: a[1] = val; break;
            case 2: a[2] = val; break;
            default: a[3] = val; break;
        }
    }
}

// DPP move: result = src from DPP-selected lane; lanes with no valid source keep old(=x)
template <int CTRL>
__device__ __forceinline__ float dpp_mov_f(float x) {
    return __int_as_float(__builtin_amdgcn_update_dpp(
        __float_as_int(x), __float_as_int(x), CTRL, 0xf, 0xf, false));
}
// full-wave min. AMD-documented reduction: row_shr 1,2,4,8 accumulates toward lane
// 15/31/47/63 of each 16-row; row_bcast:15 merges row pairs (lane63 <- min rows 2-3),
// row_bcast:31 merges halves (lane63 <- global). Read lane 63.
__device__ __forceinline__ float wave_min64(float x) {
    x = fminf(x, dpp_mov_f<0x111>(x));  // row_shr:1
    x = fminf(x, dpp_mov_f<0x112>(x));  // row_shr:2
    x = fminf(x, dpp_mov_f<0x114>(x));  // row_shr:4
    x = fminf(x, dpp_mov_f<0x118>(x));  // row_shr:8
    x = fminf(x, dpp_mov_f<0x142>(x));  // row_bcast:15
    x = fminf(x, dpp_mov_f<0x143>(x));  // row_bcast:31
    return rlf(x, 63);
}

// ---- exact JV LAP, one block (1 wave, 64 lanes) per batch, 4 cols/lane ----
template <bool USE_WS>
__global__ __launch_bounds__(64)
void lap_kernel(const float* __restrict__ costs,
                const void* __restrict__ mask,
                const float* __restrict__ cmat,
                int* __restrict__ out) {
    const int b    = blockIdx.x;
    const int lane = threadIdx.x;   // lane owns rows/cols lane*4 .. lane*4+3

    __shared__ float sp_s[NN];
    __shared__ int   tmp_s[NN];

    const int fmt = mask_fmt(mask);

    // n = count of valid objects (mask is prefix-true)
    int nloc = 0;
    #pragma unroll
    for (int r = 0; r < 4; ++r)
        nloc += mask_at(mask, fmt, b * NN + lane * 4 + r) ? 1 : 0;
    #pragma unroll
    for (int off = 32; off; off >>= 1) nloc += __shfl_xor(nloc, off);
    const int n = nloc;

    // distributed state (registers): lane k holds element 4k+r
    float u[4]  = {0.f, 0.f, 0.f, 0.f};   // row potentials
    float v[4]  = {0.f, 0.f, 0.f, 0.f};   // col potentials
    int  c4r[4] = {-1, -1, -1, -1};       // col4row (by row)
    int  r4c[4] = {-1, -1, -1, -1};       // row4col (by col)

    const float* CM = cmat + (size_t)b * NN * NN;   // transposed+masked
    const float* CB = costs + (size_t)b * NN * NN;  // raw (fallback)

    for (int cur = 0; cur < NN; ++cur) {
        // ---- Dijkstra shortest augmenting path (bit-exact vs reference) ----
        float sp[4]  = {INFV, INFV, INFV, INFV};
        int  path[4] = {-1, -1, -1, -1};
        int   SCm = 0, SRm = 0;           // per-lane 4-bit masks
        int   i      = cur;               // wave-uniform
        float minVal = 0.0f;              // wave-uniform
        int   sink   = -1;

        // guaranteed to terminate within NN iterations (each adds a col to SC,
        // and an unmatched col always exists); guard turns any bug into a
        // wrong answer instead of a hang.
        for (int guard = 0; guard <= NN && sink < 0; ++guard) {
            if (lane == (i >> 2)) SRm |= 1 << (i & 3);

            float cc[4];
            if (USE_WS) {
                const float4 c4 = *reinterpret_cast<const float4*>(CM + (size_t)i * NN + lane * 4);
                cc[0] = c4.x; cc[1] = c4.y; cc[2] = c4.z; cc[3] = c4.w;
            } else {
                if (i < n) {
                    #pragma unroll
                    for (int r = 0; r < 4; ++r)
                        cc[r] = CB[(size_t)(lane * 4 + r) * NN + i];
                } else {
                    #pragma unroll
                    for (int r = 0; r < 4; ++r) cc[r] = 0.0f;
                }
            }
            const float u_i = read4f(u, i);   // uniform scalar

            float m[4];
            #pragma unroll
            for (int r = 0; r < 4; ++r) {
                // exact reference op order: ((minVal + c) - u_i) - v_j
                const float rr = minVal + cc[r] - u_i - v[r];
                const bool sc = (SCm >> r) & 1;
                if (!sc && rr < sp[r]) { sp[r] = rr; path[r] = i; }
                m[r] = sc ? INFV : sp[r];
            }

            // wave-wide min of m, then FIRST column index achieving it (== jnp.argmin)
            minVal = wave_min64(fminf(fminf(m[0], m[1]), fminf(m[2], m[3])));

            int cand = 4;
            if (m[3] == minVal) cand = 3;
            if (m[2] == minVal) cand = 2;
            if (m[1] == minVal) cand = 1;
            if (m[0] == minVal) cand = 0;
            const unsigned long long bal = __ballot(cand < 4);
            const int fl = (bal == 0ull) ? 0 : (__ffsll((long long)bal) - 1);
            const int j  = (bal == 0ull) ? 0 : (fl * 4 + rl(cand, fl));

            if (lane == (j >> 2)) SCm |= 1 << (j & 3);
            const int nxt = read4i(r4c, j);
            if (nxt < 0) sink = j;
            else         i = nxt;
        }

        // dump sp for the dual-update gather (only LDS use, 1x per outer iter)
        *reinterpret_cast<float4*>(&sp_s[lane * 4]) = make_float4(sp[0], sp[1], sp[2], sp[3]);
        __syncthreads();

        // ---- dual updates (select semantics, same elementwise ops as reference) ----
        #pragma unroll
        for (int r = 0; r < 4; ++r) {
            const int row = lane * 4 + r;
            if ((SRm >> r) & 1) {
                float du;
                if (row == cur) {
                    du = minVal;
                } else {
                    int c = c4r[r];
                    c = c < 0 ? 0 : c;            // clip like reference
                    du = minVal - sp_s[c];
                }
                u[r] = u[r] + du;
            }
            if ((SCm >> r) & 1) v[r] = v[r] - (minVal - sp[r]);
        }
        __syncthreads();

        // ---- augment along alternating path (wave-uniform walk, registers) ----
        {
            int j = sink;
            for (int guard = 0; guard < NN; ++guard) {
                const int ii = read4i(path, j);
                write4i(r4c, j, ii, lane);
                const int jn = read4i(c4r, ii);
                write4i(c4r, ii, j, lane);
                if (ii == cur) break;
                j = jn;
            }
        }
    }

    // ---- emit output ----
    int* ob = out + b * NN;
    #pragma unroll
    for (int r = 0; r < 4; ++r) {
        const int row = lane * 4 + r;
        if (row < n) ob[row] = c4r[r];
        tmp_s[lane * 4 + r] = r4c[r];
    }
    __syncthreads();
    if (lane == 0) {
        int cnt = 0;
        for (int c = 0; c < NN; ++c) {
            if (tmp_s[c] >= n) {      // column assigned to an invalid row => unused
                ob[n + cnt] = c;
                ++cnt;
            }
        }
    }
}

extern "C" void kernel_launch(void* const* d_in, const int* in_sizes, int n_in,
                              void* d_out, int out_size, void* d_ws, size_t ws_size,
                              hipStream_t stream) {
    const float* costs = (const float*)d_in[0];
    const void*  mask  = d_in[1];
    int*         out   = (int*)d_out;

    const int B = in_sizes[1] / NN;   // in_sizes[1] = B*N
    const size_t need = (size_t)B * NN * NN * sizeof(float);

    if (ws_size >= need && d_ws != nullptr) {
        float* ws = (float*)d_ws;
        transpose_mask_kernel<<<dim3(NN / 32, NN / 32, B), dim3(32, 8), 0, stream>>>(costs, mask, ws);
        lap_kernel<true><<<dim3(B), dim3(64), 0, stream>>>(costs, mask, ws, out);
    } else {
        lap_kernel<false><<<dim3(B), dim3(64), 0, stream>>>(costs, mask, nullptr, out);
    }
}

// Round 4
// 5676.247 us; speedup vs baseline: 2.4376x; 1.0448x over previous
//
#include <hip/hip_runtime.h>

#define NN 256
#define INFV 1e30f

// ---- mask format handling (bool may arrive as bytes, int32, or float32) ----
__device__ __forceinline__ int mask_fmt(const void* m) {
    int w0 = ((const int*)m)[0];          // mask[0][0] is always true (lengths >= N/2)
    if (w0 == 1) return 0;                // int32 0/1
    if (w0 == 0x3F800000) return 1;       // float32 1.0f
    return 2;                             // 1-byte bool
}
__device__ __forceinline__ bool mask_at(const void* m, int fmt, int idx) {
    if (fmt == 0) return ((const int*)m)[idx] != 0;
    if (fmt == 1) return ((const float*)m)[idx] != 0.0f;
    return ((const unsigned char*)m)[idx] != 0;
}

// ---- tiled transpose + mask: ws[b][i][j] = mask[b][i] ? costs[b][j][i] : 0 ----
__global__ void transpose_mask_kernel(const float* __restrict__ costs,
                                      const void* __restrict__ mask,
                                      float* __restrict__ ws) {
    __shared__ float tile[32][33];
    const int b  = blockIdx.z;
    const int i0 = blockIdx.x * 32;
    const int j0 = blockIdx.y * 32;
    const int tx = threadIdx.x;   // 0..31
    const int ty = threadIdx.y;   // 0..7
    const int fmt = mask_fmt(mask);
    const float* Cb = costs + (size_t)b * NN * NN;
    float* Wb = ws + (size_t)b * NN * NN;

    #pragma unroll
    for (int k = 0; k < 32; k += 8) {
        tile[ty + k][tx] = Cb[(size_t)(j0 + ty + k) * NN + (i0 + tx)];
    }
    __syncthreads();
    #pragma unroll
    for (int k = 0; k < 32; k += 8) {
        const int i = i0 + ty + k;
        const int j = j0 + tx;
        const bool mv = mask_at(mask, fmt, b * NN + i);
        Wb[(size_t)i * NN + j] = mv ? tile[tx][ty + k] : 0.0f;
    }
}

// ---------- cross-lane helpers ----------
__device__ __forceinline__ int rl(int v, int lane) {
    return __builtin_amdgcn_readlane(v, lane);
}
__device__ __forceinline__ float rlf(float v, int lane) {
    return __int_as_float(__builtin_amdgcn_readlane(__float_as_int(v), lane));
}
// read element idx (uniform, 0..255) from a distributed array: lane k holds elems 4k..4k+3
__device__ __forceinline__ int read4i(const int a[4], int idx) {
    const int lane = idx >> 2;
    const int v0 = rl(a[0], lane), v1 = rl(a[1], lane);
    const int v2 = rl(a[2], lane), v3 = rl(a[3], lane);
    const int lo = (idx & 1) ? v1 : v0;
    const int hi = (idx & 1) ? v3 : v2;
    return (idx & 2) ? hi : lo;
}
__device__ __forceinline__ float read4f(const float a[4], int idx) {
    const int lane = idx >> 2;
    const int v0 = rl(__float_as_int(a[0]), lane), v1 = rl(__float_as_int(a[1]), lane);
    const int v2 = rl(__float_as_int(a[2]), lane), v3 = rl(__float_as_int(a[3]), lane);
    const int lo = (idx & 1) ? v1 : v0;
    const int hi = (idx & 1) ? v3 : v2;
    return __int_as_float((idx & 2) ? hi : lo);
}
// write val to distributed array element idx (idx uniform)
__device__ __forceinline__ void write4i(int (&a)[4], int idx, int val, int lane) {
    if (lane == (idx >> 2)) {
        switch (idx & 3) {
            case 0: a[0] = val; break;
            case 1: a[1] = val; break;
            case 2: a[2] = val; break;
            default: a[3] = val; break;
        }
    }
}

// DPP move: result = src from DPP-selected lane; lanes with no valid source keep old(=x)
template <int CTRL>
__device__ __forceinline__ float dpp_mov_f(float x) {
    return __int_as_float(__builtin_amdgcn_update_dpp(
        __float_as_int(x), __float_as_int(x), CTRL, 0xf, 0xf, false));
}
// full-wave min: row_shr 1,2,4,8 accumulates toward lane 15/31/47/63 of each 16-row;
// row_bcast:15 merges row pairs, row_bcast:31 merges halves (lane 63 <- global min).
__device__ __forceinline__ float wave_min64(float x) {
    x = fminf(x, dpp_mov_f<0x111>(x));  // row_shr:1
    x = fminf(x, dpp_mov_f<0x112>(x));  // row_shr:2
    x = fminf(x, dpp_mov_f<0x114>(x));  // row_shr:4
    x = fminf(x, dpp_mov_f<0x118>(x));  // row_shr:8
    x = fminf(x, dpp_mov_f<0x142>(x));  // row_bcast:15
    x = fminf(x, dpp_mov_f<0x143>(x));  // row_bcast:31
    return rlf(x, 63);
}

// ---- exact JV LAP, one block (1 wave, 64 lanes) per batch, 4 cols/lane ----
// rcache = number of leading rows of the (transposed+masked) cost matrix held in
// dynamic LDS (populated in the prologue). 0 disables the cache.
template <bool USE_WS>
__global__ __launch_bounds__(64)
void lap_kernel(const float* __restrict__ costs,
                const void* __restrict__ mask,
                const float* __restrict__ cmat,
                int* __restrict__ out,
                int rcache) {
    extern __shared__ float ldsrows[];   // [rcache][NN]

    const int b    = blockIdx.x;
    const int lane = threadIdx.x;   // lane owns rows/cols lane*4 .. lane*4+3

    __shared__ float sp_s[NN];
    __shared__ int   tmp_s[NN];

    const int fmt = mask_fmt(mask);

    // n = count of valid objects (mask is prefix-true)
    int nloc = 0;
    #pragma unroll
    for (int r = 0; r < 4; ++r)
        nloc += mask_at(mask, fmt, b * NN + lane * 4 + r) ? 1 : 0;
    #pragma unroll
    for (int off = 32; off; off >>= 1) nloc += __shfl_xor(nloc, off);
    const int n = nloc;

    // distributed state (registers): lane k holds element 4k+r
    float u[4]  = {0.f, 0.f, 0.f, 0.f};   // row potentials
    float v[4]  = {0.f, 0.f, 0.f, 0.f};   // col potentials
    int  c4r[4] = {-1, -1, -1, -1};       // col4row (by row)
    int  r4c[4] = {-1, -1, -1, -1};       // row4col (by col)

    const float* CM = cmat + (size_t)b * NN * NN;   // transposed+masked
    const float* CB = costs + (size_t)b * NN * NN;  // raw (fallback)

    // ---- prologue: stage leading rows into LDS (one row per iteration) ----
    if (USE_WS) {
        #pragma unroll 4
        for (int row = 0; row < rcache; ++row) {
            const int base = row * NN + lane * 4;
            *reinterpret_cast<float4*>(&ldsrows[base]) =
                *reinterpret_cast<const float4*>(CM + base);
        }
        __syncthreads();
    }

    for (int cur = 0; cur < NN; ++cur) {
        // ---- Dijkstra shortest augmenting path (bit-exact vs reference) ----
        float sp[4]  = {INFV, INFV, INFV, INFV};
        int  path[4] = {-1, -1, -1, -1};
        int   SCm = 0, SRm = 0;           // per-lane 4-bit masks
        int   i      = cur;               // wave-uniform
        float minVal = 0.0f;              // wave-uniform
        int   sink   = -1;

        // terminates within NN iterations (each adds a col to SC and an
        // unmatched col always exists); guard turns bugs into wrong answers,
        // never hangs.
        for (int guard = 0; guard <= NN && sink < 0; ++guard) {
            if (lane == (i >> 2)) SRm |= 1 << (i & 3);

            float cc[4];
            if (USE_WS) {
                if (i < rcache) {   // wave-uniform scalar branch (i is readlane'd)
                    const float4 c4 = *reinterpret_cast<const float4*>(&ldsrows[i * NN + lane * 4]);
                    cc[0] = c4.x; cc[1] = c4.y; cc[2] = c4.z; cc[3] = c4.w;
                } else {
                    const float4 c4 = *reinterpret_cast<const float4*>(CM + (size_t)i * NN + lane * 4);
                    cc[0] = c4.x; cc[1] = c4.y; cc[2] = c4.z; cc[3] = c4.w;
                }
            } else {
                if (i < n) {
                    #pragma unroll
                    for (int r = 0; r < 4; ++r)
                        cc[r] = CB[(size_t)(lane * 4 + r) * NN + i];
                } else {
                    #pragma unroll
                    for (int r = 0; r < 4; ++r) cc[r] = 0.0f;
                }
            }
            const float u_i = read4f(u, i);   // uniform scalar

            float m[4];
            #pragma unroll
            for (int r = 0; r < 4; ++r) {
                // exact reference op order: ((minVal + c) - u_i) - v_j
                const float rr = minVal + cc[r] - u_i - v[r];
                const bool sc = (SCm >> r) & 1;
                if (!sc && rr < sp[r]) { sp[r] = rr; path[r] = i; }
                m[r] = sc ? INFV : sp[r];
            }

            // wave-wide min of m, then FIRST column index achieving it (== jnp.argmin)
            minVal = wave_min64(fminf(fminf(m[0], m[1]), fminf(m[2], m[3])));

            int cand = 4;
            if (m[3] == minVal) cand = 3;
            if (m[2] == minVal) cand = 2;
            if (m[1] == minVal) cand = 1;
            if (m[0] == minVal) cand = 0;
            const unsigned long long bal = __ballot(cand < 4);
            const int fl = (bal == 0ull) ? 0 : (__ffsll((long long)bal) - 1);
            const int j  = (bal == 0ull) ? 0 : (fl * 4 + rl(cand, fl));

            if (lane == (j >> 2)) SCm |= 1 << (j & 3);
            const int nxt = read4i(r4c, j);
            if (nxt < 0) sink = j;
            else         i = nxt;
        }

        // dump sp for the dual-update gather (only per-outer LDS use)
        *reinterpret_cast<float4*>(&sp_s[lane * 4]) = make_float4(sp[0], sp[1], sp[2], sp[3]);
        __syncthreads();

        // ---- dual updates (select semantics, same elementwise ops as reference) ----
        #pragma unroll
        for (int r = 0; r < 4; ++r) {
            const int row = lane * 4 + r;
            if ((SRm >> r) & 1) {
                float du;
                if (row == cur) {
                    du = minVal;
                } else {
                    int c = c4r[r];
                    c = c < 0 ? 0 : c;            // clip like reference
                    du = minVal - sp_s[c];
                }
                u[r] = u[r] + du;
            }
            if ((SCm >> r) & 1) v[r] = v[r] - (minVal - sp[r]);
        }
        __syncthreads();

        // ---- augment along alternating path (wave-uniform walk, registers) ----
        {
            int j = sink;
            for (int guard = 0; guard < NN; ++guard) {
                const int ii = read4i(path, j);
                write4i(r4c, j, ii, lane);
                const int jn = read4i(c4r, ii);
                write4i(c4r, ii, j, lane);
                if (ii == cur) break;
                j = jn;
            }
        }
    }

    // ---- emit output ----
    int* ob = out + b * NN;
    #pragma unroll
    for (int r = 0; r < 4; ++r) {
        const int row = lane * 4 + r;
        if (row < n) ob[row] = c4r[r];
        tmp_s[lane * 4 + r] = r4c[r];
    }
    __syncthreads();
    if (lane == 0) {
        int cnt = 0;
        for (int c = 0; c < NN; ++c) {
            if (tmp_s[c] >= n) {      // column assigned to an invalid row => unused
                ob[n + cnt] = c;
                ++cnt;
            }
        }
    }
}

extern "C" void kernel_launch(void* const* d_in, const int* in_sizes, int n_in,
                              void* d_out, int out_size, void* d_ws, size_t ws_size,
                              hipStream_t stream) {
    const float* costs = (const float*)d_in[0];
    const void*  mask  = d_in[1];
    int*         out   = (int*)d_out;

    const int B = in_sizes[1] / NN;   // in_sizes[1] = B*N
    const size_t need = (size_t)B * NN * NN * sizeof(float);

    if (ws_size >= need && d_ws != nullptr) {
        float* ws = (float*)d_ws;
        transpose_mask_kernel<<<dim3(NN / 32, NN / 32, B), dim3(32, 8), 0, stream>>>(costs, mask, ws);

        // Try for a 158-row (158 KB) LDS row cache (gfx950: 160 KB/CU, and with
        // 64 blocks on 256 CUs occupancy doesn't matter). hipFuncSetAttribute is
        // host-side (not a stream op) -> graph-capture safe. If the attribute is
        // rejected, fall back to 60 rows (60 KB dynamic + 2 KB static < 64 KB default).
        int rcache = 158;
        hipError_t e = hipFuncSetAttribute(
            reinterpret_cast<const void*>(&lap_kernel<true>),
            hipFuncAttributeMaxDynamicSharedMemorySize,
            rcache * NN * (int)sizeof(float));
        if (e != hipSuccess) rcache = 60;
        const size_t dynbytes = (size_t)rcache * NN * sizeof(float);

        lap_kernel<true><<<dim3(B), dim3(64), dynbytes, stream>>>(costs, mask, ws, out, rcache);
    } else {
        lap_kernel<false><<<dim3(B), dim3(64), 0, stream>>>(costs, mask, nullptr, out, 0);
    }
}